// Round 12
// baseline (11.907 us; speedup 1.0000x reference)
//
#include <hip/hip_runtime.h>
#include <hip/hip_fp16.h>

// LocalAttention: B=1, H=8, S=2048, D=64, window +/-64 (129 positions), fp32 io.
// R11 base (11.48us) + window-tile skipping + s_setprio around MFMA clusters.
// 256 blocks (1/CU), 512 threads (8 waves): t = w&3 (q-tile), half = w>>2.
// q-tile t needs staged rows [16t, 16t+143] only -> wave (t,half) runs chunks
// cc in [max(t>>1,3h), min((t+8)>>1,3h+2)]; tile 2cc+t2 computed iff in
// [t, t+8], else P slot zero-filled (<=1 zero slot/wave). QK tiles 48->36,
// PV chunks 24->20, exp -25% per block. All bounds wave-uniform (scalar branch).
// Staging: T14 async-split (all 12 K/V float4 to regs, then cvt+scatter).
// K row-major f16 LDS (stride 72h), V^T f16 LDS (384B stride + 16B XOR swizzle),
// Q frags from global. h = blockIdx.x & 7 keeps each head on one XCD's L2.
// Split-k combine via LDS + one barrier.

#define SEQ 2048
#define QB 64
#define ROWS 192
#define PSTR 40          // P strip stride in halfs (80 B)

typedef _Float16 f16x8 __attribute__((ext_vector_type(8)));
typedef float    f32x4 __attribute__((ext_vector_type(4)));

static __device__ __forceinline__ ushort4 pack4(float4 f) {
    union { _Float16 h[4]; ushort4 u; } p;
    p.h[0] = (_Float16)f.x;
    p.h[1] = (_Float16)f.y;
    p.h[2] = (_Float16)f.z;
    p.h[3] = (_Float16)f.w;
    return p.u;
}

__global__ __launch_bounds__(512) void local_attn(
    const float* __restrict__ q,
    const float* __restrict__ k,
    const float* __restrict__ v,
    float* __restrict__ out)
{
    __shared__ __align__(16) _Float16      Kl[ROWS * 72];     // 27648 B
    __shared__ __align__(16) unsigned char VtB[64 * 384];     // 24576 B
    __shared__ __align__(16) _Float16      Pm[8][16 * PSTR];  // 10240 B
    __shared__ __align__(16) float         Cmb[4][64][20];    // 20480 B

    const int tid  = threadIdx.x;
    const int lane = tid & 63;
    const int w    = tid >> 6;           // 0..7
    const int t    = w & 3;              // q-tile 0..3
    const int half = w >> 2;             // 0: chunks 0-2, 1: chunks 3-5
    const int l15  = lane & 15;
    const int l4   = lane >> 4;
    const int bx   = blockIdx.x;
    const int h     = bx & 7;            // head == XCD (round-robin dispatch)
    const int qbase = (bx >> 3) * QB;

    const float* qh = q + (size_t)h * SEQ * 64;
    const float* kh = k + (size_t)h * SEQ * 64;
    const float* vh = v + (size_t)h * SEQ * 64;

    // ---- Q loads
    const float* qrow = qh + (size_t)(qbase + t * 16 + l15) * 64 + l4 * 8;
    float4 q0 = *(const float4*)(qrow);
    float4 q1 = *(const float4*)(qrow + 4);
    float4 q2 = *(const float4*)(qrow + 32);
    float4 q3 = *(const float4*)(qrow + 36);

    // ---- staging phase A: issue ALL 12 K/V loads (clamped rows, no branches)
    const int d4  = (tid & 15) << 2;     // fixed dims 0,4,...,60
    const int lr0 = tid >> 4;            // 0..31; rows advance by 32/iter
    float4 kv[6], vv[6];
    #pragma unroll
    for (int it = 0; it < 6; ++it) {
        int g = qbase - 64 + lr0 + it * 32;
        g = g < 0 ? 0 : (g > SEQ - 1 ? SEQ - 1 : g);
        kv[it] = *(const float4*)(kh + (size_t)g * 64 + d4);
        vv[it] = *(const float4*)(vh + (size_t)g * 64 + d4);
    }

    // ---- pack Q A-fragments (1/sqrt(64)=0.125 folded in) while loads fly
    union uf { f16x8 v; _Float16 hh[8]; };
    uf A0, A1;
    A0.hh[0] = (_Float16)(q0.x * 0.125f); A0.hh[1] = (_Float16)(q0.y * 0.125f);
    A0.hh[2] = (_Float16)(q0.z * 0.125f); A0.hh[3] = (_Float16)(q0.w * 0.125f);
    A0.hh[4] = (_Float16)(q1.x * 0.125f); A0.hh[5] = (_Float16)(q1.y * 0.125f);
    A0.hh[6] = (_Float16)(q1.z * 0.125f); A0.hh[7] = (_Float16)(q1.w * 0.125f);
    A1.hh[0] = (_Float16)(q2.x * 0.125f); A1.hh[1] = (_Float16)(q2.y * 0.125f);
    A1.hh[2] = (_Float16)(q2.z * 0.125f); A1.hh[3] = (_Float16)(q2.w * 0.125f);
    A1.hh[4] = (_Float16)(q3.x * 0.125f); A1.hh[5] = (_Float16)(q3.y * 0.125f);
    A1.hh[6] = (_Float16)(q3.z * 0.125f); A1.hh[7] = (_Float16)(q3.w * 0.125f);

    // ---- staging phase B: convert + scatter to LDS (loads drain in order)
    #pragma unroll
    for (int it = 0; it < 6; ++it) {
        const int lr = lr0 + it * 32;
        *(ushort4*)&Kl[lr * 72 + d4] = pack4(kv[it]);
        #pragma unroll
        for (int i2 = 0; i2 < 4; ++i2) {
            const int d = d4 + i2;
            const int u = (lr >> 3) ^ (d & 7);
            *(_Float16*)&VtB[d * 384 + (u << 4) + (lr & 7) * 2] =
                (_Float16)vv[it][i2];
        }
    }
    __syncthreads();

    // ---- main loop: wave-private chunks, window-clipped
    _Float16* Pw = Pm[w];
    float rsum[4] = {0.f, 0.f, 0.f, 0.f};
    f32x4 o[4];
    #pragma unroll
    for (int dt = 0; dt < 4; ++dt) o[dt] = (f32x4){0.f, 0.f, 0.f, 0.f};

    const int tile_lo = t;           // valid 16-row tiles for this q-tile
    const int tile_hi = t + 8;
    const int cc_lo   = max(tile_lo >> 1, half * 3);
    const int cc_hi   = min(tile_hi >> 1, half * 3 + 2);

    for (int cc = cc_lo; cc <= cc_hi; ++cc) {   // wave-uniform bounds
        const int r0 = cc * 32;

        // QK^T for this 32-row chunk: 2 tiles, each clipped to the window
        #pragma unroll
        for (int t2 = 0; t2 < 2; ++t2) {
            const int tile = 2 * cc + t2;
            if (tile >= tile_lo && tile <= tile_hi) {      // wave-uniform
                const int r = r0 + t2 * 16 + l15;          // staged row (C col)
                f16x8 b0 = *(const f16x8*)&Kl[r * 72 + l4 * 8];
                f16x8 b1 = *(const f16x8*)&Kl[r * 72 + 32 + l4 * 8];
                f32x4 cacc = {0.f, 0.f, 0.f, 0.f};
                __builtin_amdgcn_s_setprio(1);
                cacc = __builtin_amdgcn_mfma_f32_16x16x32_f16(A0.v, b0, cacc, 0, 0, 0);
                cacc = __builtin_amdgcn_mfma_f32_16x16x32_f16(A1.v, b1, cacc, 0, 0, 0);
                __builtin_amdgcn_s_setprio(0);
                const int g  = qbase - 64 + r;
                const bool gv = (g >= 0) & (g < SEQ);
                #pragma unroll
                for (int j = 0; j < 4; ++j) {
                    const int qg = qbase + t * 16 + l4 * 4 + j;  // global query
                    const bool valid = gv && (g >= qg - 64) && (g <= qg + 64);
                    const float e = valid ? __expf(cacc[j]) : 0.f;
                    rsum[j] += e;
                    Pw[(l4 * 4 + j) * PSTR + t2 * 16 + l15] = (_Float16)e;
                }
            } else {
                // dead tile inside a live chunk: zero its P slot
                #pragma unroll
                for (int j = 0; j < 4; ++j)
                    Pw[(l4 * 4 + j) * PSTR + t2 * 16 + l15] = (_Float16)0.f;
            }
        }

        // same-wave DS order; drain so P reads see the writes
        asm volatile("s_waitcnt lgkmcnt(0)" ::: "memory");

        // PV: A = P chunk (lane l15 = query), B = V^T (lane l15 = dim)
        f16x8 a = *(const f16x8*)&Pw[l15 * PSTR + l4 * 8];
        __builtin_amdgcn_s_setprio(1);
        #pragma unroll
        for (int dt = 0; dt < 4; ++dt) {
            const int dim = dt * 16 + l15;
            const int u   = ((r0 + l4 * 8) >> 3) ^ (dim & 7);
            f16x8 bb = *(const f16x8*)&VtB[dim * 384 + (u << 4)];
            o[dt] = __builtin_amdgcn_mfma_f32_16x16x32_f16(a, bb, o[dt], 0, 0, 0);
        }
        __builtin_amdgcn_s_setprio(0);
    }

    // ---- split-k combine: half-1 waves publish partials; half-0 waves merge
    if (half == 1) {
        #pragma unroll
        for (int dt = 0; dt < 4; ++dt)
            *(f32x4*)&Cmb[t][lane][dt * 4] = o[dt];
        f32x4 pr = {rsum[0], rsum[1], rsum[2], rsum[3]};
        *(f32x4*)&Cmb[t][lane][16] = pr;
    }
    __syncthreads();
    if (half == 0) {
        #pragma unroll
        for (int dt = 0; dt < 4; ++dt) {
            f32x4 p = *(const f32x4*)&Cmb[t][lane][dt * 4];
            o[dt] += p;
        }
        f32x4 pr = *(const f32x4*)&Cmb[t][lane][16];

        #pragma unroll
        for (int j = 0; j < 4; ++j) {
            float l = rsum[j] + pr[j];
            l += __shfl_xor(l, 1, 64);
            l += __shfl_xor(l, 2, 64);
            l += __shfl_xor(l, 4, 64);
            l += __shfl_xor(l, 8, 64);
            const float inv = 1.0f / l;
            const int qg = qbase + t * 16 + l4 * 4 + j;
            #pragma unroll
            for (int dt = 0; dt < 4; ++dt)
                out[((size_t)h * SEQ + qg) * 64 + dt * 16 + l15] = o[dt][j] * inv;
        }
    }
}

extern "C" void kernel_launch(void* const* d_in, const int* in_sizes, int n_in,
                              void* d_out, int out_size, void* d_ws, size_t ws_size,
                              hipStream_t stream)
{
    const float* q = (const float*)d_in[0];
    const float* k = (const float*)d_in[1];
    const float* v = (const float*)d_in[2];
    float* out = (float*)d_out;

    // 256 blocks = 1 per CU; low 3 bits = head -> one head per XCD (L2 locality)
    local_attn<<<256, 512, 0, stream>>>(q, k, v, out);
}

// Round 13
// 11.569 us; speedup vs baseline: 1.0293x; 1.0293x over previous
//
#include <hip/hip_runtime.h>
#include <hip/hip_fp16.h>

// LocalAttention: B=1, H=8, S=2048, D=64, window +/-64 (129 positions), fp32 io.
// 3-way split-k MFMA design. 256 blocks (1/CU), 768 threads (12 waves, 3/SIMD).
// t = w&3 (q-tile), third = w>>2 (chunks {0,1}/{2,3}/{4,5} of 192 staged rows).
// Per 32-row chunk: QK (2 tiles x 2 MFMA) -> exp -> wave-local P strip -> PV
// (4 dtiles x 1 MFMA); P ordering is same-wave DS program order.
// Staging: T14 async-split (all 8 K/V float4 to regs first, then cvt+scatter).
// K row-major f16 LDS (stride 72h), V^T f16 LDS (384B stride + 16B XOR swizzle),
// Q frags from global. h = blockIdx.x & 7 keeps each head on one XCD's L2.
// 3-way combine: thirds 1,2 publish f32 partials to LDS; third 0 merges.

#define SEQ 2048
#define QB 64
#define ROWS 192
#define PSTR 40          // P strip stride in halfs (80 B)

typedef _Float16 f16x8 __attribute__((ext_vector_type(8)));
typedef float    f32x4 __attribute__((ext_vector_type(4)));

static __device__ __forceinline__ ushort4 pack4(float4 f) {
    union { _Float16 h[4]; ushort4 u; } p;
    p.h[0] = (_Float16)f.x;
    p.h[1] = (_Float16)f.y;
    p.h[2] = (_Float16)f.z;
    p.h[3] = (_Float16)f.w;
    return p.u;
}

__global__ __launch_bounds__(768) void local_attn(
    const float* __restrict__ q,
    const float* __restrict__ k,
    const float* __restrict__ v,
    float* __restrict__ out)
{
    __shared__ __align__(16) _Float16      Kl[ROWS * 72];       // 27648 B
    __shared__ __align__(16) unsigned char VtB[64 * 384];       // 24576 B
    __shared__ __align__(16) _Float16      Pm[12][16 * PSTR];   // 15360 B
    __shared__ __align__(16) float         Cmb[2][4][64][20];   // 40960 B

    const int tid  = threadIdx.x;
    const int lane = tid & 63;
    const int w    = tid >> 6;           // 0..11
    const int t    = w & 3;              // q-tile 0..3
    const int third = w >> 2;            // 0,1,2: chunks {0,1},{2,3},{4,5}
    const int l15  = lane & 15;
    const int l4   = lane >> 4;
    const int bx   = blockIdx.x;
    const int h     = bx & 7;            // head == XCD (round-robin dispatch)
    const int qbase = (bx >> 3) * QB;

    const float* qh = q + (size_t)h * SEQ * 64;
    const float* kh = k + (size_t)h * SEQ * 64;
    const float* vh = v + (size_t)h * SEQ * 64;

    // ---- Q loads
    const float* qrow = qh + (size_t)(qbase + t * 16 + l15) * 64 + l4 * 8;
    float4 q0 = *(const float4*)(qrow);
    float4 q1 = *(const float4*)(qrow + 4);
    float4 q2 = *(const float4*)(qrow + 32);
    float4 q3 = *(const float4*)(qrow + 36);

    // ---- staging phase A: issue ALL 8 K/V loads (clamped rows, no branches)
    const int d4  = (tid & 15) << 2;     // fixed dims 0,4,...,60
    const int lr0 = tid >> 4;            // 0..47; rows advance by 48/iter
    float4 kv[4], vv[4];
    #pragma unroll
    for (int it = 0; it < 4; ++it) {
        int g = qbase - 64 + lr0 + it * 48;
        g = g < 0 ? 0 : (g > SEQ - 1 ? SEQ - 1 : g);
        kv[it] = *(const float4*)(kh + (size_t)g * 64 + d4);
        vv[it] = *(const float4*)(vh + (size_t)g * 64 + d4);
    }

    // ---- pack Q A-fragments (1/sqrt(64)=0.125 folded in) while loads fly
    union uf { f16x8 v; _Float16 hh[8]; };
    uf A0, A1;
    A0.hh[0] = (_Float16)(q0.x * 0.125f); A0.hh[1] = (_Float16)(q0.y * 0.125f);
    A0.hh[2] = (_Float16)(q0.z * 0.125f); A0.hh[3] = (_Float16)(q0.w * 0.125f);
    A0.hh[4] = (_Float16)(q1.x * 0.125f); A0.hh[5] = (_Float16)(q1.y * 0.125f);
    A0.hh[6] = (_Float16)(q1.z * 0.125f); A0.hh[7] = (_Float16)(q1.w * 0.125f);
    A1.hh[0] = (_Float16)(q2.x * 0.125f); A1.hh[1] = (_Float16)(q2.y * 0.125f);
    A1.hh[2] = (_Float16)(q2.z * 0.125f); A1.hh[3] = (_Float16)(q2.w * 0.125f);
    A1.hh[4] = (_Float16)(q3.x * 0.125f); A1.hh[5] = (_Float16)(q3.y * 0.125f);
    A1.hh[6] = (_Float16)(q3.z * 0.125f); A1.hh[7] = (_Float16)(q3.w * 0.125f);

    // ---- staging phase B: convert + scatter to LDS (loads drain in order)
    #pragma unroll
    for (int it = 0; it < 4; ++it) {
        const int lr = lr0 + it * 48;
        *(ushort4*)&Kl[lr * 72 + d4] = pack4(kv[it]);
        #pragma unroll
        for (int i2 = 0; i2 < 4; ++i2) {
            const int d = d4 + i2;
            const int u = (lr >> 3) ^ (d & 7);
            *(_Float16*)&VtB[d * 384 + (u << 4) + (lr & 7) * 2] =
                (_Float16)vv[it][i2];
        }
    }
    __syncthreads();

    // ---- main loop: wave-private, 2 chunks per wave
    _Float16* Pw = Pm[w];
    float rsum[4] = {0.f, 0.f, 0.f, 0.f};
    f32x4 o[4];
    #pragma unroll
    for (int dt = 0; dt < 4; ++dt) o[dt] = (f32x4){0.f, 0.f, 0.f, 0.f};

    #pragma unroll
    for (int c = 0; c < 2; ++c) {
        const int r0 = (third * 2 + c) * 32;

        // QK^T for this 32-row chunk: 2 tiles
        #pragma unroll
        for (int t2 = 0; t2 < 2; ++t2) {
            const int r = r0 + t2 * 16 + l15;          // staged row (C col)
            f16x8 b0 = *(const f16x8*)&Kl[r * 72 + l4 * 8];
            f16x8 b1 = *(const f16x8*)&Kl[r * 72 + 32 + l4 * 8];
            f32x4 cacc = {0.f, 0.f, 0.f, 0.f};
            cacc = __builtin_amdgcn_mfma_f32_16x16x32_f16(A0.v, b0, cacc, 0, 0, 0);
            cacc = __builtin_amdgcn_mfma_f32_16x16x32_f16(A1.v, b1, cacc, 0, 0, 0);
            const int g  = qbase - 64 + r;
            const bool gv = (g >= 0) & (g < SEQ);
            #pragma unroll
            for (int j = 0; j < 4; ++j) {
                const int qg = qbase + t * 16 + l4 * 4 + j;   // global query (C row)
                const bool valid = gv && (g >= qg - 64) && (g <= qg + 64);
                const float e = valid ? __expf(cacc[j]) : 0.f;
                rsum[j] += e;
                Pw[(l4 * 4 + j) * PSTR + t2 * 16 + l15] = (_Float16)e;
            }
        }

        // same-wave DS order; drain so P reads see the writes
        asm volatile("s_waitcnt lgkmcnt(0)" ::: "memory");

        // PV: A = P chunk (lane l15 = query), B = V^T (lane l15 = dim)
        f16x8 a = *(const f16x8*)&Pw[l15 * PSTR + l4 * 8];
        #pragma unroll
        for (int dt = 0; dt < 4; ++dt) {
            const int dim = dt * 16 + l15;
            const int u   = ((r0 + l4 * 8) >> 3) ^ (dim & 7);
            f16x8 bb = *(const f16x8*)&VtB[dim * 384 + (u << 4)];
            o[dt] = __builtin_amdgcn_mfma_f32_16x16x32_f16(a, bb, o[dt], 0, 0, 0);
        }
    }

    // ---- 3-way combine: thirds 1,2 publish partials; third 0 merges
    if (third > 0) {
        float* Cl = &Cmb[third - 1][t][lane][0];
        #pragma unroll
        for (int dt = 0; dt < 4; ++dt)
            *(f32x4*)(Cl + dt * 4) = o[dt];
        f32x4 pr = {rsum[0], rsum[1], rsum[2], rsum[3]};
        *(f32x4*)(Cl + 16) = pr;
    }
    __syncthreads();
    if (third == 0) {
        const float* C1 = &Cmb[0][t][lane][0];
        const float* C2 = &Cmb[1][t][lane][0];
        #pragma unroll
        for (int dt = 0; dt < 4; ++dt) {
            f32x4 p1 = *(const f32x4*)(C1 + dt * 4);
            f32x4 p2 = *(const f32x4*)(C2 + dt * 4);
            o[dt] += p1 + p2;
        }
        f32x4 r1 = *(const f32x4*)(C1 + 16);
        f32x4 r2 = *(const f32x4*)(C2 + 16);

        #pragma unroll
        for (int j = 0; j < 4; ++j) {
            float l = rsum[j] + r1[j] + r2[j];
            l += __shfl_xor(l, 1, 64);
            l += __shfl_xor(l, 2, 64);
            l += __shfl_xor(l, 4, 64);
            l += __shfl_xor(l, 8, 64);
            const float inv = 1.0f / l;
            const int qg = qbase + t * 16 + l4 * 4 + j;
            #pragma unroll
            for (int dt = 0; dt < 4; ++dt)
                out[((size_t)h * SEQ + qg) * 64 + dt * 16 + l15] = o[dt][j] * inv;
        }
    }
}

extern "C" void kernel_launch(void* const* d_in, const int* in_sizes, int n_in,
                              void* d_out, int out_size, void* d_ws, size_t ws_size,
                              hipStream_t stream)
{
    const float* q = (const float*)d_in[0];
    const float* k = (const float*)d_in[1];
    const float* v = (const float*)d_in[2];
    float* out = (float*)d_out;

    // 256 blocks = 1 per CU; low 3 bits = head -> one head per XCD (L2 locality)
    local_attn<<<256, 768, 0, stream>>>(q, k, v, out);
}